// Round 7
// baseline (431.393 us; speedup 1.0000x reference)
//
#include <hip/hip_runtime.h>

#define N_NODES 100000
#define N_EDGES 1600000
#define IN_DIM 128
#define HID 64
#define NB 782               // ceil(100000 / 128) buckets of 128 nodes
#define NBLK_GEMM 782        // ceil(100000 / 128) gemm blocks (128 rows each)
#define NGROUP4 25000        // N_NODES / 4 fused-agg blocks (1 node per wave)

typedef __attribute__((ext_vector_type(8))) _Float16 h8v;
typedef __attribute__((ext_vector_type(4))) float f4v;

struct Args {
  const float* x; const int* ei;
  const float* Wp; const float* bp;
  const float* W1; const float* b1;
  const float* W2; const float* b2;
  const float* W3; const float* b3;
  float* out;
  _Float16* bufA16; _Float16* hw16;
  int* pairs; int* csr; int* offs; float* dinv;
  int* bsz; int* bboff; int* bcur;
  _Float16* WpH; _Float16* WpL; _Float16* W1H; _Float16* W1L;
  _Float16* W2H; _Float16* W2L; _Float16* W3H; _Float16* W3L;
};

// f16(lo/hi half of dword) * f32 + f32 accumulate, single VALU op
__device__ __forceinline__ void fmix_lo(float& acc, unsigned hv, float w) {
  asm("v_fma_mix_f32 %0, %1, %2, %0 op_sel:[0,0,0] op_sel_hi:[1,0,0]"
      : "+v"(acc) : "v"(hv), "v"(w));
}
__device__ __forceinline__ void fmix_hi(float& acc, unsigned hv, float w) {
  asm("v_fma_mix_f32 %0, %1, %2, %0 op_sel:[1,0,0] op_sel_hi:[1,0,0]"
      : "+v"(acc) : "v"(hv), "v"(w));
}

// ---------------- weight prep: split fp32 W[K][64] -> transposed half hi/lo ----
__device__ __forceinline__ void d_split(const float* __restrict__ W,
                                        _Float16* __restrict__ hi,
                                        _Float16* __restrict__ lo, int K, int i) {
  int k = i >> 6, n = i & 63;
  float v = W[i];
  _Float16 h = (_Float16)v;
  float r = v - (float)h;
  hi[n * K + k] = h;
  lo[n * K + k] = (_Float16)r;
}

__global__ __launch_bounds__(256) void f_prep(Args a) {
  int blk = blockIdx.x, t = threadIdx.x;
  if (blk < 32) d_split(a.Wp, a.WpH, a.WpL, IN_DIM, blk * 256 + t);
  else if (blk < 48) d_split(a.W1, a.W1H, a.W1L, HID, (blk - 32) * 256 + t);
  else if (blk < 64) d_split(a.W2, a.W2H, a.W2L, HID, (blk - 48) * 256 + t);
  else d_split(a.W3, a.W3H, a.W3L, HID, (blk - 64) * 256 + t);
}

// ---------------- bucket histogram ----------------
__global__ __launch_bounds__(256) void f_bhist(Args a) {
  __shared__ int cnt[NB];
  int t = threadIdx.x;
  for (int i = t; i < NB; i += 256) cnt[i] = 0;
  __syncthreads();
  int e0 = blockIdx.x * 8192, e1 = min(e0 + 8192, N_EDGES);
  for (int e = e0 + t; e < e1; e += 256)
    atomicAdd(&cnt[a.ei[N_EDGES + e] >> 7], 1);
  __syncthreads();
  for (int i = t; i < NB; i += 256)
    if (cnt[i]) atomicAdd(&a.bsz[i], cnt[i]);
}

// ---------------- bucket exclusive scan (1 block, 256 thr x 4 slots) ----------
__global__ __launch_bounds__(256) void f_bscan(Args a) {
  __shared__ int sm[256];
  int t = threadIdx.x;
  int c[4];
  int idx0 = t * 4;
#pragma unroll
  for (int j = 0; j < 4; ++j) c[j] = (idx0 + j < NB) ? a.bsz[idx0 + j] : 0;
  int tsum = c[0] + c[1] + c[2] + c[3];
  int val = tsum;
  sm[t] = val;
  __syncthreads();
  for (int off = 1; off < 256; off <<= 1) {
    int u = (t >= off) ? sm[t - off] : 0;
    __syncthreads();
    val += u;
    sm[t] = val;
    __syncthreads();
  }
  int excl = val - tsum;
#pragma unroll
  for (int j = 0; j < 4; ++j) {
    int idx = idx0 + j;
    if (idx < NB) { a.bboff[idx] = excl; a.bcur[idx] = excl; }
    excl += c[j];
  }
  if (t == 255) a.bboff[NB] = val;  // == N_EDGES
}

// ---------------- partition edges into buckets; pack (dlocal<<17 | src) --------
__global__ __launch_bounds__(256) void f_partition(Args a) {
  __shared__ int cnt[NB];
  __shared__ int base[NB];
  int t = threadIdx.x;
  for (int i = t; i < NB; i += 256) cnt[i] = 0;
  __syncthreads();
  int e0 = blockIdx.x * 8192, e1 = min(e0 + 8192, N_EDGES);
  for (int e = e0 + t; e < e1; e += 256)
    atomicAdd(&cnt[a.ei[N_EDGES + e] >> 7], 1);
  __syncthreads();
  for (int i = t; i < NB; i += 256) {
    int c = cnt[i];
    base[i] = c ? atomicAdd(&a.bcur[i], c) : 0;
    cnt[i] = 0;
  }
  __syncthreads();
  for (int e = e0 + t; e < e1; e += 256) {
    int s = a.ei[e];
    int d = a.ei[N_EDGES + e];
    int b = d >> 7;
    int r = atomicAdd(&cnt[b], 1);
    a.pairs[base[b] + r] = ((d & 127) << 17) | s;
  }
}

// ---------------- per-bucket degrees + offs + dinv + CSR scatter ---------------
// csr stores src << 7 (byte offset of the 128B fp16 row)
__global__ __launch_bounds__(256) void f_csrdeg(Args a) {
  __shared__ int ldeg[128];
  __shared__ int sc[128];
  __shared__ int lcur[128];
  int t = threadIdx.x;
  int b = blockIdx.x;
  int node0 = b << 7;
  int nloc = min(128, N_NODES - node0);
  int beg = a.bboff[b], end = a.bboff[b + 1];
  if (t < 128) ldeg[t] = 0;
  __syncthreads();
  for (int i = beg + t; i < end; i += 256)
    atomicAdd(&ldeg[(a.pairs[i] >> 17) & 127], 1);
  __syncthreads();
  int dv = (t < 128) ? ldeg[t] : 0;
  if (t < 128) sc[t] = dv;
  __syncthreads();
  for (int off = 1; off < 128; off <<= 1) {
    int u = (t >= off && t < 128) ? sc[t - off] : 0;
    __syncthreads();
    if (t < 128) sc[t] += u;
    __syncthreads();
  }
  if (t < nloc) {
    int o = beg + sc[t] - dv;
    a.offs[node0 + t] = o;
    lcur[t] = o;
    a.dinv[node0 + t] = rsqrtf((float)dv + 1.0f);
  }
  if (b == NB - 1 && t == 0) a.offs[N_NODES] = N_EDGES;
  __syncthreads();
  for (int i = beg + t; i < end; i += 256) {
    int p = a.pairs[i];
    int pos = atomicAdd(&lcur[(p >> 17) & 127], 1);
    a.csr[pos] = (p & 131071) << 7;
  }
}

// ---- pre GEMM v2: LDS-staged swizzled weights, 2 frags/wave, dbuf x prefetch ----
__global__ __launch_bounds__(256) void f_gemm_pre(Args a) {
  __shared__ _Float16 sW[2 * 64 * IN_DIM];  // hi | lo halves, XOR-swizzled (32 KB)
  int t = threadIdx.x;
  int wave = t >> 6, lane = t & 63, fi = lane & 15, quad = lane >> 4;
  int r0 = blockIdx.x * 128 + wave * 32;

  f4v xb0[8], xb1[8];
  {
    int row = r0 + fi; if (row >= N_NODES) row = N_NODES - 1;
    const float* xp = a.x + (size_t)row * IN_DIM + quad * 8;
#pragma unroll
    for (int j = 0; j < 4; ++j) {
      xb0[2 * j]     = *(const f4v*)(xp + j * 32);
      xb0[2 * j + 1] = *(const f4v*)(xp + j * 32 + 4);
    }
  }
#pragma unroll
  for (int i = 0; i < 8; ++i) {
    int c = i * 256 + t;               // 0..2047
    int h = c >> 10;                   // 0 = hi, 1 = lo
    int c2 = c & 1023;                 // chunk within half
    int n = c2 >> 4;                   // output-col row (16 chunks per row)
    const _Float16* src = (h ? a.WpL : a.WpH) + c2 * 8;
    f4v v = *(const f4v*)src;
    int off = (h << 14) | ((c2 * 16) ^ ((n & 7) << 4));
    *(f4v*)((char*)sW + off) = v;
  }
  __syncthreads();

  float bv[4];
#pragma unroll
  for (int ct = 0; ct < 4; ++ct) bv[ct] = a.bp[ct * 16 + fi];

#pragma unroll
  for (int f = 0; f < 2; ++f) {
    f4v* xcur = (f & 1) ? xb1 : xb0;
    f4v* xnxt = (f & 1) ? xb0 : xb1;
    if (f < 1) {
      int row = r0 + 16 + fi; if (row >= N_NODES) row = N_NODES - 1;
      const float* xp = a.x + (size_t)row * IN_DIM + quad * 8;
#pragma unroll
      for (int j = 0; j < 4; ++j) {
        xnxt[2 * j]     = *(const f4v*)(xp + j * 32);
        xnxt[2 * j + 1] = *(const f4v*)(xp + j * 32 + 4);
      }
    }
    f4v acc[4];
#pragma unroll
    for (int ct = 0; ct < 4; ++ct) acc[ct] = (f4v){0.f, 0.f, 0.f, 0.f};
#pragma unroll
    for (int k0i = 0; k0i < 4; ++k0i) {
      h8v ah, al;
#pragma unroll
      for (int j = 0; j < 4; ++j) {
        float v0 = xcur[2 * k0i][j], v1 = xcur[2 * k0i + 1][j];
        _Float16 h0 = (_Float16)v0, h1 = (_Float16)v1;
        ah[j] = h0;     al[j] = (_Float16)(v0 - (float)h0);
        ah[4 + j] = h1; al[4 + j] = (_Float16)(v1 - (float)h1);
      }
#pragma unroll
      for (int ct = 0; ct < 4; ++ct) {
        int n = ct * 16 + fi;
        int bo = ((n * IN_DIM + k0i * 32 + quad * 8) * 2) ^ ((n & 7) << 4);
        h8v bh = *(const h8v*)((const char*)sW + bo);
        h8v bl = *(const h8v*)((const char*)sW + 16384 + bo);
        acc[ct] = __builtin_amdgcn_mfma_f32_16x16x32_f16(ah, bh, acc[ct], 0, 0, 0);
        acc[ct] = __builtin_amdgcn_mfma_f32_16x16x32_f16(al, bh, acc[ct], 0, 0, 0);
        acc[ct] = __builtin_amdgcn_mfma_f32_16x16x32_f16(ah, bl, acc[ct], 0, 0, 0);
      }
    }
    int ro = r0 + f * 16;
#pragma unroll
    for (int ct = 0; ct < 4; ++ct) {
#pragma unroll
      for (int j = 0; j < 4; ++j) {
        int orow = ro + quad * 4 + j;
        if (orow < N_NODES)
          a.bufA16[(size_t)orow * HID + ct * 16 + fi] = (_Float16)(acc[ct][j] + bv[ct]);
      }
    }
  }
}

// ---- fused aggregate + GEMM (v8): 1 node PER WAVE (R4 gather shape) ---------
// agg(h W) == (agg h) W. Block = 4 nodes x 4 waves; wave w owns node node0+w,
// running round-4's proven oct-parallel 2-deep gather verbatim (49 µs shape).
// MFMA A-tile is 16 rows: rows 0-3 = real g (hi/lo), rows 4-15 zeroed at entry
// (disjoint addresses -> no race with the row 0-3 writes; both precede the
// barrier). Wasted MFMA rows are free (MfmaUtil ~1.5%).
template <int MODE>
__global__ __launch_bounds__(256) void f_aggw(Args a, const _Float16* __restrict__ hsrc,
                                              const _Float16* __restrict__ Wh,
                                              const _Float16* __restrict__ Wl,
                                              const float* __restrict__ bias,
                                              _Float16* __restrict__ out16,
                                              float* __restrict__ out32) {
  __shared__ char sG[2][2048];     // [hi|lo][16 rows x 128B], byte ^= (row&7)<<4
  __shared__ float sSS[4][4];      // per-wave partial sum-of-squares (MODE 1)
  int t = threadIdx.x;
  int wave = t >> 6, lane = t & 63, oct = lane >> 3, fi = lane & 7;
  int node0 = blockIdx.x * 4;      // N_NODES == 25000*4, no bounds checks
  int node = node0 + wave;
  const char* hwb = (const char*)hsrc;
  int lb = fi * 16;

  // zero pad rows 4..15 of both LDS buffers (192 16B-chunks, disjoint from rows 0-3)
  if (t < 192) {
    int buf = t / 96, c2 = t % 96;
    int row = 4 + (c2 >> 3), cir = c2 & 7;
    int off = (row * 128 + cir * 16) ^ ((row & 7) << 4);
    *(uint4*)(&sG[buf][0] + off) = make_uint4(0, 0, 0, 0);
  }

  // ---- phase 1: round-4 gather, one node per wave ----
  float di = a.dinv[node];
  int beg = a.offs[node];
  int end = a.offs[node + 1];

  float acc[8];
#pragma unroll
  for (int c = 0; c < 8; ++c) acc[c] = 0.f;

  if (oct == 0) {  // self-loop: h_self * di (post-scale by di -> di^2)
    uint4 hv = *(const uint4*)(hwb + ((size_t)node << 7) + lb);
    fmix_lo(acc[0], hv.x, di); fmix_hi(acc[1], hv.x, di);
    fmix_lo(acc[2], hv.y, di); fmix_hi(acc[3], hv.y, di);
    fmix_lo(acc[4], hv.z, di); fmix_hi(acc[5], hv.z, di);
    fmix_lo(acc[6], hv.w, di); fmix_hi(acc[7], hv.w, di);
  }
  for (int e0 = beg + oct; e0 < end; e0 += 16) {
    int off0 = a.csr[e0];
    int e1 = e0 + 8;
    bool v1 = e1 < end;
    int off1 = a.csr[v1 ? e1 : beg];
    float w0 = a.dinv[(unsigned)off0 >> 7];
    float w1 = v1 ? a.dinv[(unsigned)off1 >> 7] : 0.0f;
    uint4 h0 = *(const uint4*)(hwb + (unsigned)off0 + lb);
    uint4 h1 = *(const uint4*)(hwb + (unsigned)off1 + lb);
    fmix_lo(acc[0], h0.x, w0); fmix_hi(acc[1], h0.x, w0);
    fmix_lo(acc[2], h0.y, w0); fmix_hi(acc[3], h0.y, w0);
    fmix_lo(acc[4], h0.z, w0); fmix_hi(acc[5], h0.z, w0);
    fmix_lo(acc[6], h0.w, w0); fmix_hi(acc[7], h0.w, w0);
    fmix_lo(acc[0], h1.x, w1); fmix_hi(acc[1], h1.x, w1);
    fmix_lo(acc[2], h1.y, w1); fmix_hi(acc[3], h1.y, w1);
    fmix_lo(acc[4], h1.z, w1); fmix_hi(acc[5], h1.z, w1);
    fmix_lo(acc[6], h1.w, w1); fmix_hi(acc[7], h1.w, w1);
  }
#pragma unroll
  for (int c = 0; c < 8; ++c) {
    float v = acc[c];
    v += __shfl_xor(v, 8);
    v += __shfl_xor(v, 16);
    v += __shfl_xor(v, 32);
    acc[c] = v;
  }
  if (oct == 0) {  // g = acc * di, split hi/lo, stage to LDS row = wave
    int row = wave;
    h8v gh, gl;
#pragma unroll
    for (int c = 0; c < 8; ++c) {
      float g = acc[c] * di;
      _Float16 h = (_Float16)g;
      gh[c] = h;
      gl[c] = (_Float16)(g - (float)h);
    }
    int off = (row * 128 + fi * 16) ^ ((row & 7) << 4);
    *(h8v*)(&sG[0][0] + off) = gh;
    *(h8v*)(&sG[1][0] + off) = gl;
  }
  __syncthreads();

  // ---- phase 2: wave w -> out-ch tile [w*16, w*16+16) for rows 0..15 (0-3 real)
  int r15 = lane & 15, quad = lane >> 4;
  f4v acc4 = {0.f, 0.f, 0.f, 0.f};
#pragma unroll
  for (int k0i = 0; k0i < 2; ++k0i) {
    int ao = (r15 * 128 + k0i * 64 + quad * 16) ^ ((r15 & 7) << 4);
    h8v ah = *(const h8v*)(&sG[0][0] + ao);
    h8v al = *(const h8v*)(&sG[1][0] + ao);
    size_t bo = (size_t)(wave * 16 + r15) * HID + k0i * 32 + quad * 8;
    h8v bh = *(const h8v*)(Wh + bo);
    h8v bl = *(const h8v*)(Wl + bo);
    acc4 = __builtin_amdgcn_mfma_f32_16x16x32_f16(ah, bh, acc4, 0, 0, 0);
    acc4 = __builtin_amdgcn_mfma_f32_16x16x32_f16(al, bh, acc4, 0, 0, 0);
    acc4 = __builtin_amdgcn_mfma_f32_16x16x32_f16(ah, bl, acc4, 0, 0, 0);
  }
  // C layout: node-row = quad*4 + j (only 0..3 real), out-ch = wave*16 + r15
  float bv = bias[wave * 16 + r15];
  if (MODE == 0) {
    if (quad == 0) {
#pragma unroll
      for (int j = 0; j < 4; ++j) {
        out16[(size_t)(node0 + j) * HID + wave * 16 + r15] =
            (_Float16)fmaxf(acc4[j] + bv, 0.f);
      }
    }
  } else {
    float val[4], ssj[4];
#pragma unroll
    for (int j = 0; j < 4; ++j) { val[j] = acc4[j] + bv; ssj[j] = val[j] * val[j]; }
#pragma unroll
    for (int m = 1; m < 16; m <<= 1) {
#pragma unroll
      for (int j = 0; j < 4; ++j) ssj[j] += __shfl_xor(ssj[j], m);
    }
    if (lane == 0) {  // quad 0, r15 0 holds reduced ssj for rows 0..3
#pragma unroll
      for (int j = 0; j < 4; ++j) sSS[wave][j] = ssj[j];
    }
    __syncthreads();
    if (quad == 0) {
#pragma unroll
      for (int j = 0; j < 4; ++j) {
        float tot = sSS[0][j] + sSS[1][j] + sSS[2][j] + sSS[3][j];
        float sc = 1.0f / fmaxf(sqrtf(tot), 1e-12f);
        out32[(size_t)(node0 + j) * HID + wave * 16 + r15] = val[j] * sc;
      }
    }
  }
}

extern "C" void kernel_launch(void* const* d_in, const int* in_sizes, int n_in,
                              void* d_out, int out_size, void* d_ws, size_t ws_size,
                              hipStream_t stream) {
  char* ws = (char*)d_ws;
  Args a;
  a.x  = (const float*)d_in[0];
  a.ei = (const int*)d_in[1];
  a.Wp = (const float*)d_in[2];  a.bp = (const float*)d_in[3];
  a.W1 = (const float*)d_in[4];  a.b1 = (const float*)d_in[5];
  a.W2 = (const float*)d_in[6];  a.b2 = (const float*)d_in[7];
  a.W3 = (const float*)d_in[8];  a.b3 = (const float*)d_in[9];
  a.out  = (float*)d_out;
  a.bufA16 = (_Float16*)(ws + 0);             // 12.8 MB fp16 activations A0
  a.hw16   = (_Float16*)(ws + 12800000);      // 12.8 MB fp16 activations A1
  a.pairs  = (int*)(ws + 25600000);           // 6.4 MB packed (dlocal<<17|src)
  a.csr    = (int*)(ws + 32000000);           // 6.4 MB (src byte offsets)
  a.offs   = (int*)(ws + 38400000);           // (N+1) ints
  a.dinv   = (float*)(ws + 38800016);         // 400 KB
  a.bsz    = (int*)(ws + 39200016);           // NB ints
  a.bboff  = (int*)(ws + 39203152);           // NB+1 ints
  a.bcur   = (int*)(ws + 39206288);           // NB ints
  a.WpH = (_Float16*)(ws + 39210000);         // 16 KB
  a.WpL = (_Float16*)(ws + 39226384);
  a.W1H = (_Float16*)(ws + 39242768);         // 8 KB each
  a.W1L = (_Float16*)(ws + 39250960);
  a.W2H = (_Float16*)(ws + 39259152);
  a.W2L = (_Float16*)(ws + 39267344);
  a.W3H = (_Float16*)(ws + 39275536);
  a.W3L = (_Float16*)(ws + 39283728);

  (void)hipMemsetAsync(a.bsz, 0, NB * sizeof(int), stream);
  f_prep<<<80, 256, 0, stream>>>(a);
  f_bhist<<<196, 256, 0, stream>>>(a);
  f_bscan<<<1, 256, 0, stream>>>(a);
  f_partition<<<196, 256, 0, stream>>>(a);
  f_csrdeg<<<NB, 256, 0, stream>>>(a);
  f_gemm_pre<<<NBLK_GEMM, 256, 0, stream>>>(a);
  f_aggw<0><<<NGROUP4, 256, 0, stream>>>(a, a.bufA16, a.W1H, a.W1L, a.b1, a.hw16, nullptr);
  f_aggw<0><<<NGROUP4, 256, 0, stream>>>(a, a.hw16, a.W2H, a.W2L, a.b2, a.bufA16, nullptr);
  f_aggw<1><<<NGROUP4, 256, 0, stream>>>(a, a.bufA16, a.W3H, a.W3L, a.b3, nullptr, a.out);
}

// Round 9
// 350.128 us; speedup vs baseline: 1.2321x; 1.2321x over previous
//
#include <hip/hip_runtime.h>

#define N_NODES 100000
#define N_EDGES 1600000
#define IN_DIM 128
#define HID 64
#define NB 782               // ceil(100000 / 128) buckets of 128 nodes
#define NBLK_GEMM 782        // ceil(100000 / 128) gemm blocks (128 rows each)
#define NGROUP80 1250        // N_NODES / 80 fused-agg blocks
#define NPW 20               // nodes per wave (sequential)

typedef __attribute__((ext_vector_type(8))) _Float16 h8v;
typedef __attribute__((ext_vector_type(4))) float f4v;

struct Args {
  const float* x; const int* ei;
  const float* Wp; const float* bp;
  const float* W1; const float* b1;
  const float* W2; const float* b2;
  const float* W3; const float* b3;
  float* out;
  _Float16* bufA16; _Float16* hw16;
  int* pairs; int* csr; int* offs; float* dinv;
  int* bsz; int* bboff; int* bcur;
  _Float16* WpH; _Float16* WpL; _Float16* W1H; _Float16* W1L;
  _Float16* W2H; _Float16* W2L; _Float16* W3H; _Float16* W3L;
};

// f16(lo/hi half of dword) * f32 + f32 accumulate, single VALU op
__device__ __forceinline__ void fmix_lo(float& acc, unsigned hv, float w) {
  asm("v_fma_mix_f32 %0, %1, %2, %0 op_sel:[0,0,0] op_sel_hi:[1,0,0]"
      : "+v"(acc) : "v"(hv), "v"(w));
}
__device__ __forceinline__ void fmix_hi(float& acc, unsigned hv, float w) {
  asm("v_fma_mix_f32 %0, %1, %2, %0 op_sel:[1,0,0] op_sel_hi:[1,0,0]"
      : "+v"(acc) : "v"(hv), "v"(w));
}

// ---------------- weight prep: split fp32 W[K][64] -> transposed half hi/lo ----
__device__ __forceinline__ void d_split(const float* __restrict__ W,
                                        _Float16* __restrict__ hi,
                                        _Float16* __restrict__ lo, int K, int i) {
  int k = i >> 6, n = i & 63;
  float v = W[i];
  _Float16 h = (_Float16)v;
  float r = v - (float)h;
  hi[n * K + k] = h;
  lo[n * K + k] = (_Float16)r;
}

__global__ __launch_bounds__(256) void f_prep(Args a) {
  int blk = blockIdx.x, t = threadIdx.x;
  if (blk < 32) d_split(a.Wp, a.WpH, a.WpL, IN_DIM, blk * 256 + t);
  else if (blk < 48) d_split(a.W1, a.W1H, a.W1L, HID, (blk - 32) * 256 + t);
  else if (blk < 64) d_split(a.W2, a.W2H, a.W2L, HID, (blk - 48) * 256 + t);
  else d_split(a.W3, a.W3H, a.W3L, HID, (blk - 64) * 256 + t);
}

// ---------------- bucket histogram ----------------
__global__ __launch_bounds__(256) void f_bhist(Args a) {
  __shared__ int cnt[NB];
  int t = threadIdx.x;
  for (int i = t; i < NB; i += 256) cnt[i] = 0;
  __syncthreads();
  int e0 = blockIdx.x * 8192, e1 = min(e0 + 8192, N_EDGES);
  for (int e = e0 + t; e < e1; e += 256)
    atomicAdd(&cnt[a.ei[N_EDGES + e] >> 7], 1);
  __syncthreads();
  for (int i = t; i < NB; i += 256)
    if (cnt[i]) atomicAdd(&a.bsz[i], cnt[i]);
}

// ---------------- bucket exclusive scan (1 block, 256 thr x 4 slots) ----------
__global__ __launch_bounds__(256) void f_bscan(Args a) {
  __shared__ int sm[256];
  int t = threadIdx.x;
  int c[4];
  int idx0 = t * 4;
#pragma unroll
  for (int j = 0; j < 4; ++j) c[j] = (idx0 + j < NB) ? a.bsz[idx0 + j] : 0;
  int tsum = c[0] + c[1] + c[2] + c[3];
  int val = tsum;
  sm[t] = val;
  __syncthreads();
  for (int off = 1; off < 256; off <<= 1) {
    int u = (t >= off) ? sm[t - off] : 0;
    __syncthreads();
    val += u;
    sm[t] = val;
    __syncthreads();
  }
  int excl = val - tsum;
#pragma unroll
  for (int j = 0; j < 4; ++j) {
    int idx = idx0 + j;
    if (idx < NB) { a.bboff[idx] = excl; a.bcur[idx] = excl; }
    excl += c[j];
  }
  if (t == 255) a.bboff[NB] = val;  // == N_EDGES
}

// ---------------- partition edges into buckets; pack (dlocal<<17 | src) --------
__global__ __launch_bounds__(256) void f_partition(Args a) {
  __shared__ int cnt[NB];
  __shared__ int base[NB];
  int t = threadIdx.x;
  for (int i = t; i < NB; i += 256) cnt[i] = 0;
  __syncthreads();
  int e0 = blockIdx.x * 8192, e1 = min(e0 + 8192, N_EDGES);
  for (int e = e0 + t; e < e1; e += 256)
    atomicAdd(&cnt[a.ei[N_EDGES + e] >> 7], 1);
  __syncthreads();
  for (int i = t; i < NB; i += 256) {
    int c = cnt[i];
    base[i] = c ? atomicAdd(&a.bcur[i], c) : 0;
    cnt[i] = 0;
  }
  __syncthreads();
  for (int e = e0 + t; e < e1; e += 256) {
    int s = a.ei[e];
    int d = a.ei[N_EDGES + e];
    int b = d >> 7;
    int r = atomicAdd(&cnt[b], 1);
    a.pairs[base[b] + r] = ((d & 127) << 17) | s;
  }
}

// ---------------- per-bucket degrees + offs + dinv + CSR scatter ---------------
// csr stores src << 7 (byte offset of the 128B fp16 row)
__global__ __launch_bounds__(256) void f_csrdeg(Args a) {
  __shared__ int ldeg[128];
  __shared__ int sc[128];
  __shared__ int lcur[128];
  int t = threadIdx.x;
  int b = blockIdx.x;
  int node0 = b << 7;
  int nloc = min(128, N_NODES - node0);
  int beg = a.bboff[b], end = a.bboff[b + 1];
  if (t < 128) ldeg[t] = 0;
  __syncthreads();
  for (int i = beg + t; i < end; i += 256)
    atomicAdd(&ldeg[(a.pairs[i] >> 17) & 127], 1);
  __syncthreads();
  int dv = (t < 128) ? ldeg[t] : 0;
  if (t < 128) sc[t] = dv;
  __syncthreads();
  for (int off = 1; off < 128; off <<= 1) {
    int u = (t >= off && t < 128) ? sc[t - off] : 0;
    __syncthreads();
    if (t < 128) sc[t] += u;
    __syncthreads();
  }
  if (t < nloc) {
    int o = beg + sc[t] - dv;
    a.offs[node0 + t] = o;
    lcur[t] = o;
    a.dinv[node0 + t] = rsqrtf((float)dv + 1.0f);
  }
  if (b == NB - 1 && t == 0) a.offs[N_NODES] = N_EDGES;
  __syncthreads();
  for (int i = beg + t; i < end; i += 256) {
    int p = a.pairs[i];
    int pos = atomicAdd(&lcur[(p >> 17) & 127], 1);
    a.csr[pos] = (p & 131071) << 7;
  }
}

// ---- pre GEMM v2: LDS-staged swizzled weights, 2 frags/wave, dbuf x prefetch ----
__global__ __launch_bounds__(256) void f_gemm_pre(Args a) {
  __shared__ _Float16 sW[2 * 64 * IN_DIM];  // hi | lo halves, XOR-swizzled (32 KB)
  int t = threadIdx.x;
  int wave = t >> 6, lane = t & 63, fi = lane & 15, quad = lane >> 4;
  int r0 = blockIdx.x * 128 + wave * 32;

  f4v xb0[8], xb1[8];
  {
    int row = r0 + fi; if (row >= N_NODES) row = N_NODES - 1;
    const float* xp = a.x + (size_t)row * IN_DIM + quad * 8;
#pragma unroll
    for (int j = 0; j < 4; ++j) {
      xb0[2 * j]     = *(const f4v*)(xp + j * 32);
      xb0[2 * j + 1] = *(const f4v*)(xp + j * 32 + 4);
    }
  }
#pragma unroll
  for (int i = 0; i < 8; ++i) {
    int c = i * 256 + t;               // 0..2047
    int h = c >> 10;                   // 0 = hi, 1 = lo
    int c2 = c & 1023;                 // chunk within half
    int n = c2 >> 4;                   // output-col row (16 chunks per row)
    const _Float16* src = (h ? a.WpL : a.WpH) + c2 * 8;
    f4v v = *(const f4v*)src;
    int off = (h << 14) | ((c2 * 16) ^ ((n & 7) << 4));
    *(f4v*)((char*)sW + off) = v;
  }
  __syncthreads();

  float bv[4];
#pragma unroll
  for (int ct = 0; ct < 4; ++ct) bv[ct] = a.bp[ct * 16 + fi];

#pragma unroll
  for (int f = 0; f < 2; ++f) {
    f4v* xcur = (f & 1) ? xb1 : xb0;
    f4v* xnxt = (f & 1) ? xb0 : xb1;
    if (f < 1) {
      int row = r0 + 16 + fi; if (row >= N_NODES) row = N_NODES - 1;
      const float* xp = a.x + (size_t)row * IN_DIM + quad * 8;
#pragma unroll
      for (int j = 0; j < 4; ++j) {
        xnxt[2 * j]     = *(const f4v*)(xp + j * 32);
        xnxt[2 * j + 1] = *(const f4v*)(xp + j * 32 + 4);
      }
    }
    f4v acc[4];
#pragma unroll
    for (int ct = 0; ct < 4; ++ct) acc[ct] = (f4v){0.f, 0.f, 0.f, 0.f};
#pragma unroll
    for (int k0i = 0; k0i < 4; ++k0i) {
      h8v ah, al;
#pragma unroll
      for (int j = 0; j < 4; ++j) {
        float v0 = xcur[2 * k0i][j], v1 = xcur[2 * k0i + 1][j];
        _Float16 h0 = (_Float16)v0, h1 = (_Float16)v1;
        ah[j] = h0;     al[j] = (_Float16)(v0 - (float)h0);
        ah[4 + j] = h1; al[4 + j] = (_Float16)(v1 - (float)h1);
      }
#pragma unroll
      for (int ct = 0; ct < 4; ++ct) {
        int n = ct * 16 + fi;
        int bo = ((n * IN_DIM + k0i * 32 + quad * 8) * 2) ^ ((n & 7) << 4);
        h8v bh = *(const h8v*)((const char*)sW + bo);
        h8v bl = *(const h8v*)((const char*)sW + 16384 + bo);
        acc[ct] = __builtin_amdgcn_mfma_f32_16x16x32_f16(ah, bh, acc[ct], 0, 0, 0);
        acc[ct] = __builtin_amdgcn_mfma_f32_16x16x32_f16(al, bh, acc[ct], 0, 0, 0);
        acc[ct] = __builtin_amdgcn_mfma_f32_16x16x32_f16(ah, bl, acc[ct], 0, 0, 0);
      }
    }
    int ro = r0 + f * 16;
#pragma unroll
    for (int ct = 0; ct < 4; ++ct) {
#pragma unroll
      for (int j = 0; j < 4; ++j) {
        int orow = ro + quad * 4 + j;
        if (orow < N_NODES)
          a.bufA16[(size_t)orow * HID + ct * 16 + fi] = (_Float16)(acc[ct][j] + bv[ct]);
      }
    }
  }
}

// ---- fused aggregate + GEMM (v9): 80-node blocks, 20 seq nodes per wave ------
// agg(h W) == (agg h) W. Block = 80 nodes (4 waves x 20 sequential nodes).
// Phase 1: R4's proven oct-parallel 2-deep gather, one node at a time per wave;
//   g hi/lo staged into swizzled LDS (all 80 rows real -> no padding, no waste).
// Phase 2: wave w owns out-channels [w*16, w*16+16): 5 node-tiles x 6 MFMAs.
//   MODE 0: bias+relu scalar stores. MODE 1: bias + L2-norm via LDS reduce.
// Big blocks amortize fixed cost (weights 1250x16KB=20MB) and shrink barrier
// slack (sum-of-20-degrees sigma ~5.6%, max over 4 waves ~+6%).
template <int MODE>
__global__ __launch_bounds__(256) void f_aggw(Args a, const _Float16* __restrict__ hsrc,
                                              const _Float16* __restrict__ Wh,
                                              const _Float16* __restrict__ Wl,
                                              const float* __restrict__ bias,
                                              _Float16* __restrict__ out16,
                                              float* __restrict__ out32) {
  __shared__ char sG[2][80 * 128];   // [hi|lo][80 rows x 128B], byte ^= (row&7)<<4
  __shared__ float sSS[4][80];       // per-wave partial sum-of-squares (MODE 1)
  int t = threadIdx.x;
  int wave = t >> 6, lane = t & 63, oct = lane >> 3, fi = lane & 7;
  int node0 = blockIdx.x * 80;       // N_NODES == 1250*80, no bounds checks
  int nbase = node0 + wave * NPW;
  const char* hwb = (const char*)hsrc;
  int lb = fi * 16;

  // ---- phase 1: gather 20 nodes sequentially (R4 shape per node) ----
  for (int n = 0; n < NPW; ++n) {
    int node = nbase + n;
    float di = a.dinv[node];
    int beg = a.offs[node];
    int end = a.offs[node + 1];

    float acc[8];
#pragma unroll
    for (int c = 0; c < 8; ++c) acc[c] = 0.f;

    if (oct == 0) {  // self-loop: h_self * di (post-scale by di -> di^2)
      uint4 hv = *(const uint4*)(hwb + ((size_t)node << 7) + lb);
      fmix_lo(acc[0], hv.x, di); fmix_hi(acc[1], hv.x, di);
      fmix_lo(acc[2], hv.y, di); fmix_hi(acc[3], hv.y, di);
      fmix_lo(acc[4], hv.z, di); fmix_hi(acc[5], hv.z, di);
      fmix_lo(acc[6], hv.w, di); fmix_hi(acc[7], hv.w, di);
    }
    for (int e0 = beg + oct; e0 < end; e0 += 16) {
      int off0 = a.csr[e0];
      int e1 = e0 + 8;
      bool v1 = e1 < end;
      int off1 = a.csr[v1 ? e1 : beg];
      float w0 = a.dinv[(unsigned)off0 >> 7];
      float w1 = v1 ? a.dinv[(unsigned)off1 >> 7] : 0.0f;
      uint4 h0 = *(const uint4*)(hwb + (unsigned)off0 + lb);
      uint4 h1 = *(const uint4*)(hwb + (unsigned)off1 + lb);
      fmix_lo(acc[0], h0.x, w0); fmix_hi(acc[1], h0.x, w0);
      fmix_lo(acc[2], h0.y, w0); fmix_hi(acc[3], h0.y, w0);
      fmix_lo(acc[4], h0.z, w0); fmix_hi(acc[5], h0.z, w0);
      fmix_lo(acc[6], h0.w, w0); fmix_hi(acc[7], h0.w, w0);
      fmix_lo(acc[0], h1.x, w1); fmix_hi(acc[1], h1.x, w1);
      fmix_lo(acc[2], h1.y, w1); fmix_hi(acc[3], h1.y, w1);
      fmix_lo(acc[4], h1.z, w1); fmix_hi(acc[5], h1.z, w1);
      fmix_lo(acc[6], h1.w, w1); fmix_hi(acc[7], h1.w, w1);
    }
#pragma unroll
    for (int c = 0; c < 8; ++c) {
      float v = acc[c];
      v += __shfl_xor(v, 8);
      v += __shfl_xor(v, 16);
      v += __shfl_xor(v, 32);
      acc[c] = v;
    }
    if (oct == 0) {  // g = acc * di, split hi/lo, stage to LDS
      int row = wave * NPW + n;
      h8v gh, gl;
#pragma unroll
      for (int c = 0; c < 8; ++c) {
        float g = acc[c] * di;
        _Float16 h = (_Float16)g;
        gh[c] = h;
        gl[c] = (_Float16)(g - (float)h);
      }
      int off = (row * 128 + fi * 16) ^ ((row & 7) << 4);
      *(h8v*)(&sG[0][0] + off) = gh;
      *(h8v*)(&sG[1][0] + off) = gl;
    }
  }
  __syncthreads();

  // ---- phase 2: wave w -> out-ch tile [w*16, w*16+16), 5 node-tiles of 16 ----
  int r15 = lane & 15, quad = lane >> 4;
  float bv = bias[wave * 16 + r15];
  // weights for this wave's channel tile (L2-resident, 4 KB/wave)
  h8v Bh[2], Bl[2];
#pragma unroll
  for (int k0i = 0; k0i < 2; ++k0i) {
    size_t bo = (size_t)(wave * 16 + r15) * HID + k0i * 32 + quad * 8;
    Bh[k0i] = *(const h8v*)(Wh + bo);
    Bl[k0i] = *(const h8v*)(Wl + bo);
  }
  float val[5][4];
#pragma unroll
  for (int nt = 0; nt < 5; ++nt) {
    f4v acc4 = {0.f, 0.f, 0.f, 0.f};
    int row = nt * 16 + r15;
#pragma unroll
    for (int k0i = 0; k0i < 2; ++k0i) {
      int ao = (row * 128 + k0i * 64 + quad * 16) ^ ((row & 7) << 4);
      h8v ah = *(const h8v*)(&sG[0][0] + ao);
      h8v al = *(const h8v*)(&sG[1][0] + ao);
      acc4 = __builtin_amdgcn_mfma_f32_16x16x32_f16(ah, Bh[k0i], acc4, 0, 0, 0);
      acc4 = __builtin_amdgcn_mfma_f32_16x16x32_f16(al, Bh[k0i], acc4, 0, 0, 0);
      acc4 = __builtin_amdgcn_mfma_f32_16x16x32_f16(ah, Bl[k0i], acc4, 0, 0, 0);
    }
    if (MODE == 0) {
#pragma unroll
      for (int j = 0; j < 4; ++j) {
        int nl = nt * 16 + quad * 4 + j;
        out16[(size_t)(node0 + nl) * HID + wave * 16 + r15] =
            (_Float16)fmaxf(acc4[j] + bv, 0.f);
      }
    } else {
      float ssj[4];
#pragma unroll
      for (int j = 0; j < 4; ++j) {
        val[nt][j] = acc4[j] + bv;
        ssj[j] = val[nt][j] * val[nt][j];
      }
#pragma unroll
      for (int m = 1; m < 16; m <<= 1) {
#pragma unroll
        for (int j = 0; j < 4; ++j) ssj[j] += __shfl_xor(ssj[j], m);
      }
      if (r15 == 0) {
#pragma unroll
        for (int j = 0; j < 4; ++j) sSS[wave][nt * 16 + quad * 4 + j] = ssj[j];
      }
    }
  }
  if (MODE == 1) {
    __syncthreads();
#pragma unroll
    for (int nt = 0; nt < 5; ++nt) {
#pragma unroll
      for (int j = 0; j < 4; ++j) {
        int nl = nt * 16 + quad * 4 + j;
        float tot = sSS[0][nl] + sSS[1][nl] + sSS[2][nl] + sSS[3][nl];
        float sc = 1.0f / fmaxf(sqrtf(tot), 1e-12f);
        out32[(size_t)(node0 + nl) * HID + wave * 16 + r15] = val[nt][j] * sc;
      }
    }
  }
}

extern "C" void kernel_launch(void* const* d_in, const int* in_sizes, int n_in,
                              void* d_out, int out_size, void* d_ws, size_t ws_size,
                              hipStream_t stream) {
  char* ws = (char*)d_ws;
  Args a;
  a.x  = (const float*)d_in[0];
  a.ei = (const int*)d_in[1];
  a.Wp = (const float*)d_in[2];  a.bp = (const float*)d_in[3];
  a.W1 = (const float*)d_in[4];  a.b1 = (const float*)d_in[5];
  a.W2 = (const float*)d_in[6];  a.b2 = (const float*)d_in[7];
  a.W3 = (const float*)d_in[8];  a.b3 = (const float*)d_in[9];
  a.out  = (float*)d_out;
  a.bufA16 = (_Float16*)(ws + 0);             // 12.8 MB fp16 activations A0
  a.hw16   = (_Float16*)(ws + 12800000);      // 12.8 MB fp16 activations A1
  a.pairs  = (int*)(ws + 25600000);           // 6.4 MB packed (dlocal<<17|src)
  a.csr    = (int*)(ws + 32000000);           // 6.4 MB (src byte offsets)
  a.offs   = (int*)(ws + 38400000);           // (N+1) ints
  a.dinv   = (float*)(ws + 38800016);         // 400 KB
  a.bsz    = (int*)(ws + 39200016);           // NB ints
  a.bboff  = (int*)(ws + 39203152);           // NB+1 ints
  a.bcur   = (int*)(ws + 39206288);           // NB ints
  a.WpH = (_Float16*)(ws + 39210000);         // 16 KB
  a.WpL = (_Float16*)(ws + 39226384);
  a.W1H = (_Float16*)(ws + 39242768);         // 8 KB each
  a.W1L = (_Float16*)(ws + 39250960);
  a.W2H = (_Float16*)(ws + 39259152);
  a.W2L = (_Float16*)(ws + 39267344);
  a.W3H = (_Float16*)(ws + 39275536);
  a.W3L = (_Float16*)(ws + 39283728);

  (void)hipMemsetAsync(a.bsz, 0, NB * sizeof(int), stream);
  f_prep<<<80, 256, 0, stream>>>(a);
  f_bhist<<<196, 256, 0, stream>>>(a);
  f_bscan<<<1, 256, 0, stream>>>(a);
  f_partition<<<196, 256, 0, stream>>>(a);
  f_csrdeg<<<NB, 256, 0, stream>>>(a);
  f_gemm_pre<<<NBLK_GEMM, 256, 0, stream>>>(a);
  f_aggw<0><<<NGROUP80, 256, 0, stream>>>(a, a.bufA16, a.W1H, a.W1L, a.b1, a.hw16, nullptr);
  f_aggw<0><<<NGROUP80, 256, 0, stream>>>(a, a.hw16, a.W2H, a.W2L, a.b2, a.bufA16, nullptr);
  f_aggw<1><<<NGROUP80, 256, 0, stream>>>(a, a.bufA16, a.W3H, a.W3L, a.b3, nullptr, a.out);
}

// Round 10
// 327.673 us; speedup vs baseline: 1.3165x; 1.0685x over previous
//
#include <hip/hip_runtime.h>

#define N_NODES 100000
#define N_EDGES 1600000
#define IN_DIM 128
#define HID 64
#define NB 782               // ceil(100000 / 128) buckets of 128 nodes
#define NGROUP16 6250        // N_NODES / 16 fused-agg blocks

typedef __attribute__((ext_vector_type(8))) _Float16 h8v;
typedef __attribute__((ext_vector_type(4))) float f4v;

struct Args {
  const float* x; const int* ei;
  const float* Wp; const float* bp;
  const float* W1; const float* b1;
  const float* W2; const float* b2;
  const float* W3; const float* b3;
  float* out;
  _Float16* bufA16; _Float16* hw16;
  int* pairs; int* csr; int* offs; float* dinv;
  int* bsz; int* bboff; int* bcur;
  _Float16* WpH; _Float16* WpL; _Float16* W1H; _Float16* W1L;
  _Float16* W2H; _Float16* W2L; _Float16* W3H; _Float16* W3L;
};

// f16(lo/hi half of dword) * f32 + f32 accumulate, single VALU op
__device__ __forceinline__ void fmix_lo(float& acc, unsigned hv, float w) {
  asm("v_fma_mix_f32 %0, %1, %2, %0 op_sel:[0,0,0] op_sel_hi:[1,0,0]"
      : "+v"(acc) : "v"(hv), "v"(w));
}
__device__ __forceinline__ void fmix_hi(float& acc, unsigned hv, float w) {
  asm("v_fma_mix_f32 %0, %1, %2, %0 op_sel:[1,0,0] op_sel_hi:[1,0,0]"
      : "+v"(acc) : "v"(hv), "v"(w));
}

// ---------------- weight prep: split fp32 W[K][64] -> transposed half hi/lo ----
__device__ __forceinline__ void d_split(const float* __restrict__ W,
                                        _Float16* __restrict__ hi,
                                        _Float16* __restrict__ lo, int K, int i) {
  int k = i >> 6, n = i & 63;
  float v = W[i];
  _Float16 h = (_Float16)v;
  float r = v - (float)h;
  hi[n * K + k] = h;
  lo[n * K + k] = (_Float16)r;
}

// ---------------- fused: bhist (blocks 0..195) | weight prep (196..275) -------
__global__ __launch_bounds__(256) void f_prep_bhist(Args a) {
  __shared__ int cnt[NB];
  int blk = blockIdx.x, t = threadIdx.x;
  if (blk >= 196) {  // ---- prep branch (independent of bhist) ----
    int b2 = blk - 196;
    if (b2 < 32) d_split(a.Wp, a.WpH, a.WpL, IN_DIM, b2 * 256 + t);
    else if (b2 < 48) d_split(a.W1, a.W1H, a.W1L, HID, (b2 - 32) * 256 + t);
    else if (b2 < 64) d_split(a.W2, a.W2H, a.W2L, HID, (b2 - 48) * 256 + t);
    else d_split(a.W3, a.W3H, a.W3L, HID, (b2 - 64) * 256 + t);
    return;  // block-uniform branch; no barrier crossed
  }
  // ---- bhist branch ----
  for (int i = t; i < NB; i += 256) cnt[i] = 0;
  __syncthreads();
  int e0 = blk * 8192, e1 = min(e0 + 8192, N_EDGES);
  for (int e = e0 + t; e < e1; e += 256)
    atomicAdd(&cnt[a.ei[N_EDGES + e] >> 7], 1);
  __syncthreads();
  for (int i = t; i < NB; i += 256)
    if (cnt[i]) atomicAdd(&a.bsz[i], cnt[i]);
}

// ---------------- bucket exclusive scan (1 block, 256 thr x 4 slots) ----------
__global__ __launch_bounds__(256) void f_bscan(Args a) {
  __shared__ int sm[256];
  int t = threadIdx.x;
  int c[4];
  int idx0 = t * 4;
#pragma unroll
  for (int j = 0; j < 4; ++j) c[j] = (idx0 + j < NB) ? a.bsz[idx0 + j] : 0;
  int tsum = c[0] + c[1] + c[2] + c[3];
  int val = tsum;
  sm[t] = val;
  __syncthreads();
  for (int off = 1; off < 256; off <<= 1) {
    int u = (t >= off) ? sm[t - off] : 0;
    __syncthreads();
    val += u;
    sm[t] = val;
    __syncthreads();
  }
  int excl = val - tsum;
#pragma unroll
  for (int j = 0; j < 4; ++j) {
    int idx = idx0 + j;
    if (idx < NB) { a.bboff[idx] = excl; a.bcur[idx] = excl; }
    excl += c[j];
  }
  if (t == 255) a.bboff[NB] = val;  // == N_EDGES
}

// ---------------- partition edges into buckets; pack (dlocal<<17 | src) --------
__global__ __launch_bounds__(256) void f_partition(Args a) {
  __shared__ int cnt[NB];
  __shared__ int base[NB];
  int t = threadIdx.x;
  for (int i = t; i < NB; i += 256) cnt[i] = 0;
  __syncthreads();
  int e0 = blockIdx.x * 8192, e1 = min(e0 + 8192, N_EDGES);
  for (int e = e0 + t; e < e1; e += 256)
    atomicAdd(&cnt[a.ei[N_EDGES + e] >> 7], 1);
  __syncthreads();
  for (int i = t; i < NB; i += 256) {
    int c = cnt[i];
    base[i] = c ? atomicAdd(&a.bcur[i], c) : 0;
    cnt[i] = 0;
  }
  __syncthreads();
  for (int e = e0 + t; e < e1; e += 256) {
    int s = a.ei[e];
    int d = a.ei[N_EDGES + e];
    int b = d >> 7;
    int r = atomicAdd(&cnt[b], 1);
    a.pairs[base[b] + r] = ((d & 127) << 17) | s;
  }
}

// ---------------- csrdeg body (smem: 3*128 ints) ------------------------------
// csr stores src << 7 (byte offset of the 128B fp16 row)
__device__ __forceinline__ void d_csrdeg(Args& a, int b, char* smem) {
  int* ldeg = (int*)smem;
  int* sc = ldeg + 128;
  int* lcur = sc + 128;
  int t = threadIdx.x;
  int node0 = b << 7;
  int nloc = min(128, N_NODES - node0);
  int beg = a.bboff[b], end = a.bboff[b + 1];
  if (t < 128) ldeg[t] = 0;
  __syncthreads();
  for (int i = beg + t; i < end; i += 256)
    atomicAdd(&ldeg[(a.pairs[i] >> 17) & 127], 1);
  __syncthreads();
  int dv = (t < 128) ? ldeg[t] : 0;
  if (t < 128) sc[t] = dv;
  __syncthreads();
  for (int off = 1; off < 128; off <<= 1) {
    int u = (t >= off && t < 128) ? sc[t - off] : 0;
    __syncthreads();
    if (t < 128) sc[t] += u;
    __syncthreads();
  }
  if (t < nloc) {
    int o = beg + sc[t] - dv;
    a.offs[node0 + t] = o;
    lcur[t] = o;
    a.dinv[node0 + t] = rsqrtf((float)dv + 1.0f);
  }
  if (b == NB - 1 && t == 0) a.offs[N_NODES] = N_EDGES;
  __syncthreads();
  for (int i = beg + t; i < end; i += 256) {
    int p = a.pairs[i];
    int pos = atomicAdd(&lcur[(p >> 17) & 127], 1);
    a.csr[pos] = (p & 131071) << 7;
  }
}

// ---------------- gemm_pre body (smem: 32 KB swizzled weights) ----------------
__device__ __forceinline__ void d_gemm_pre(Args& a, int blk, char* smem) {
  _Float16* sW = (_Float16*)smem;  // hi | lo halves, XOR-swizzled
  int t = threadIdx.x;
  int wave = t >> 6, lane = t & 63, fi = lane & 15, quad = lane >> 4;
  int r0 = blk * 128 + wave * 32;

  f4v xb0[8], xb1[8];
  {
    int row = r0 + fi; if (row >= N_NODES) row = N_NODES - 1;
    const float* xp = a.x + (size_t)row * IN_DIM + quad * 8;
#pragma unroll
    for (int j = 0; j < 4; ++j) {
      xb0[2 * j]     = *(const f4v*)(xp + j * 32);
      xb0[2 * j + 1] = *(const f4v*)(xp + j * 32 + 4);
    }
  }
#pragma unroll
  for (int i = 0; i < 8; ++i) {
    int c = i * 256 + t;               // 0..2047
    int h = c >> 10;                   // 0 = hi, 1 = lo
    int c2 = c & 1023;                 // chunk within half
    int n = c2 >> 4;                   // output-col row (16 chunks per row)
    const _Float16* src = (h ? a.WpL : a.WpH) + c2 * 8;
    f4v v = *(const f4v*)src;
    int off = (h << 14) | ((c2 * 16) ^ ((n & 7) << 4));
    *(f4v*)((char*)sW + off) = v;
  }
  __syncthreads();

  float bv[4];
#pragma unroll
  for (int ct = 0; ct < 4; ++ct) bv[ct] = a.bp[ct * 16 + fi];

#pragma unroll
  for (int f = 0; f < 2; ++f) {
    f4v* xcur = (f & 1) ? xb1 : xb0;
    f4v* xnxt = (f & 1) ? xb0 : xb1;
    if (f < 1) {
      int row = r0 + 16 + fi; if (row >= N_NODES) row = N_NODES - 1;
      const float* xp = a.x + (size_t)row * IN_DIM + quad * 8;
#pragma unroll
      for (int j = 0; j < 4; ++j) {
        xnxt[2 * j]     = *(const f4v*)(xp + j * 32);
        xnxt[2 * j + 1] = *(const f4v*)(xp + j * 32 + 4);
      }
    }
    f4v acc[4];
#pragma unroll
    for (int ct = 0; ct < 4; ++ct) acc[ct] = (f4v){0.f, 0.f, 0.f, 0.f};
#pragma unroll
    for (int k0i = 0; k0i < 4; ++k0i) {
      h8v ah, al;
#pragma unroll
      for (int j = 0; j < 4; ++j) {
        float v0 = xcur[2 * k0i][j], v1 = xcur[2 * k0i + 1][j];
        _Float16 h0 = (_Float16)v0, h1 = (_Float16)v1;
        ah[j] = h0;     al[j] = (_Float16)(v0 - (float)h0);
        ah[4 + j] = h1; al[4 + j] = (_Float16)(v1 - (float)h1);
      }
#pragma unroll
      for (int ct = 0; ct < 4; ++ct) {
        int n = ct * 16 + fi;
        int bo = ((n * IN_DIM + k0i * 32 + quad * 8) * 2) ^ ((n & 7) << 4);
        h8v bh = *(const h8v*)((const char*)sW + bo);
        h8v bl = *(const h8v*)((const char*)sW + 16384 + bo);
        acc[ct] = __builtin_amdgcn_mfma_f32_16x16x32_f16(ah, bh, acc[ct], 0, 0, 0);
        acc[ct] = __builtin_amdgcn_mfma_f32_16x16x32_f16(al, bh, acc[ct], 0, 0, 0);
        acc[ct] = __builtin_amdgcn_mfma_f32_16x16x32_f16(ah, bl, acc[ct], 0, 0, 0);
      }
    }
    int ro = r0 + f * 16;
#pragma unroll
    for (int ct = 0; ct < 4; ++ct) {
#pragma unroll
      for (int j = 0; j < 4; ++j) {
        int orow = ro + quad * 4 + j;
        if (orow < N_NODES)
          a.bufA16[(size_t)orow * HID + ct * 16 + fi] = (_Float16)(acc[ct][j] + bv[ct]);
      }
    }
  }
}

// ---- fused: csrdeg (even blocks) | gemm_pre (odd blocks) ---------------------
// Independent work co-scheduled in one dispatch: csrdeg is scattered-memory +
// LDS atomics; gemm_pre is MFMA + streaming loads. Interleaved bid&1 split
// spreads both types evenly across CUs.
__global__ __launch_bounds__(256) void f_csrdeg_gemm(Args a) {
  __shared__ char smem[32768];
  int bid = blockIdx.x;
  if (bid & 1) d_gemm_pre(a, bid >> 1, smem);
  else d_csrdeg(a, bid >> 1, smem);
}

// ---- fused aggregate + GEMM (R5 16-node version, proven 60 µs) ---------------
// agg(h W) == (agg h) W. Block = 16 nodes (4 waves x 4 nodes sequential).
template <int MODE>
__global__ __launch_bounds__(256) void f_aggw(Args a, const _Float16* __restrict__ hsrc,
                                              const _Float16* __restrict__ Wh,
                                              const _Float16* __restrict__ Wl,
                                              const float* __restrict__ bias,
                                              _Float16* __restrict__ out16,
                                              float* __restrict__ out32) {
  __shared__ char sG[2][2048];     // [hi|lo][16 rows x 128B], byte ^= (row&7)<<4
  __shared__ float sSS[4][16];     // per-wave partial sum-of-squares (MODE 1)
  int t = threadIdx.x;
  int wave = t >> 6, lane = t & 63, oct = lane >> 3, fi = lane & 7;
  int node0 = blockIdx.x * 16;     // N_NODES == 6250*16, no bounds checks
  const char* hwb = (const char*)hsrc;
  int lb = fi * 16;

  for (int n = 0; n < 4; ++n) {
    int node = node0 + wave * 4 + n;
    float di = a.dinv[node];
    int beg = a.offs[node];
    int end = a.offs[node + 1];
    float acc[8];
#pragma unroll
    for (int c = 0; c < 8; ++c) acc[c] = 0.f;

    if (oct == 0) {  // self-loop: h_self * di (post-scale by di -> di^2)
      uint4 hv = *(const uint4*)(hwb + ((size_t)node << 7) + lb);
      fmix_lo(acc[0], hv.x, di); fmix_hi(acc[1], hv.x, di);
      fmix_lo(acc[2], hv.y, di); fmix_hi(acc[3], hv.y, di);
      fmix_lo(acc[4], hv.z, di); fmix_hi(acc[5], hv.z, di);
      fmix_lo(acc[6], hv.w, di); fmix_hi(acc[7], hv.w, di);
    }
    for (int e0 = beg + oct; e0 < end; e0 += 16) {
      int off0 = a.csr[e0];
      int e1 = e0 + 8;
      bool v1 = e1 < end;
      int off1 = a.csr[v1 ? e1 : beg];
      float w0 = a.dinv[(unsigned)off0 >> 7];
      float w1 = v1 ? a.dinv[(unsigned)off1 >> 7] : 0.0f;
      uint4 h0 = *(const uint4*)(hwb + (unsigned)off0 + lb);
      uint4 h1 = *(const uint4*)(hwb + (unsigned)off1 + lb);
      fmix_lo(acc[0], h0.x, w0); fmix_hi(acc[1], h0.x, w0);
      fmix_lo(acc[2], h0.y, w0); fmix_hi(acc[3], h0.y, w0);
      fmix_lo(acc[4], h0.z, w0); fmix_hi(acc[5], h0.z, w0);
      fmix_lo(acc[6], h0.w, w0); fmix_hi(acc[7], h0.w, w0);
      fmix_lo(acc[0], h1.x, w1); fmix_hi(acc[1], h1.x, w1);
      fmix_lo(acc[2], h1.y, w1); fmix_hi(acc[3], h1.y, w1);
      fmix_lo(acc[4], h1.z, w1); fmix_hi(acc[5], h1.z, w1);
      fmix_lo(acc[6], h1.w, w1); fmix_hi(acc[7], h1.w, w1);
    }
#pragma unroll
    for (int c = 0; c < 8; ++c) {
      float v = acc[c];
      v += __shfl_xor(v, 8);
      v += __shfl_xor(v, 16);
      v += __shfl_xor(v, 32);
      acc[c] = v;
    }
    if (oct == 0) {  // g = acc * di, split hi/lo, stage to LDS
      int row = wave * 4 + n;
      h8v gh, gl;
#pragma unroll
      for (int c = 0; c < 8; ++c) {
        float g = acc[c] * di;
        _Float16 h = (_Float16)g;
        gh[c] = h;
        gl[c] = (_Float16)(g - (float)h);
      }
      int off = (row * 128 + fi * 16) ^ ((row & 7) << 4);
      *(h8v*)(&sG[0][0] + off) = gh;
      *(h8v*)(&sG[1][0] + off) = gl;
    }
  }
  __syncthreads();

  // MFMA phase: wave w -> out-ch tile [w*16, w*16+16) for all 16 nodes
  int r15 = lane & 15, quad = lane >> 4;
  f4v acc4 = {0.f, 0.f, 0.f, 0.f};
#pragma unroll
  for (int k0i = 0; k0i < 2; ++k0i) {
    int ao = (r15 * 128 + k0i * 64 + quad * 16) ^ ((r15 & 7) << 4);
    h8v ah = *(const h8v*)(&sG[0][0] + ao);
    h8v al = *(const h8v*)(&sG[1][0] + ao);
    size_t bo = (size_t)(wave * 16 + r15) * HID + k0i * 32 + quad * 8;
    h8v bh = *(const h8v*)(Wh + bo);
    h8v bl = *(const h8v*)(Wl + bo);
    acc4 = __builtin_amdgcn_mfma_f32_16x16x32_f16(ah, bh, acc4, 0, 0, 0);
    acc4 = __builtin_amdgcn_mfma_f32_16x16x32_f16(al, bh, acc4, 0, 0, 0);
    acc4 = __builtin_amdgcn_mfma_f32_16x16x32_f16(ah, bl, acc4, 0, 0, 0);
  }
  // C layout: node = quad*4 + j (block-local), out-ch = wave*16 + r15
  float bv = bias[wave * 16 + r15];
  if (MODE == 0) {
#pragma unroll
    for (int j = 0; j < 4; ++j) {
      int nl = quad * 4 + j;
      out16[(size_t)(node0 + nl) * HID + wave * 16 + r15] =
          (_Float16)fmaxf(acc4[j] + bv, 0.f);
    }
  } else {
    float val[4], ssj[4];
#pragma unroll
    for (int j = 0; j < 4; ++j) { val[j] = acc4[j] + bv; ssj[j] = val[j] * val[j]; }
#pragma unroll
    for (int m = 1; m < 16; m <<= 1) {
#pragma unroll
      for (int j = 0; j < 4; ++j) ssj[j] += __shfl_xor(ssj[j], m);
    }
    if (r15 == 0) {
#pragma unroll
      for (int j = 0; j < 4; ++j) sSS[wave][quad * 4 + j] = ssj[j];
    }
    __syncthreads();
#pragma unroll
    for (int j = 0; j < 4; ++j) {
      int nl = quad * 4 + j;
      float tot = sSS[0][nl] + sSS[1][nl] + sSS[2][nl] + sSS[3][nl];
      float sc = 1.0f / fmaxf(sqrtf(tot), 1e-12f);
      out32[(size_t)(node0 + nl) * HID + wave * 16 + r15] = val[j] * sc;
    }
  }
}

extern "C" void kernel_launch(void* const* d_in, const int* in_sizes, int n_in,
                              void* d_out, int out_size, void* d_ws, size_t ws_size,
                              hipStream_t stream) {
  char* ws = (char*)d_ws;
  Args a;
  a.x  = (const float*)d_in[0];
  a.ei = (const int*)d_in[1];
  a.Wp = (const float*)d_in[2];  a.bp = (const float*)d_in[3];
  a.W1 = (const float*)d_in[4];  a.b1 = (const float*)d_in[5];
  a.W2 = (const float*)d_in[6];  a.b2 = (const float*)d_in[7];
  a.W3 = (const float*)d_in[8];  a.b3 = (const float*)d_in[9];
  a.out  = (float*)d_out;
  a.bufA16 = (_Float16*)(ws + 0);             // 12.8 MB fp16 activations A0
  a.hw16   = (_Float16*)(ws + 12800000);      // 12.8 MB fp16 activations A1
  a.pairs  = (int*)(ws + 25600000);           // 6.4 MB packed (dlocal<<17|src)
  a.csr    = (int*)(ws + 32000000);           // 6.4 MB (src byte offsets)
  a.offs   = (int*)(ws + 38400000);           // (N+1) ints
  a.dinv   = (float*)(ws + 38800016);         // 400 KB
  a.bsz    = (int*)(ws + 39200016);           // NB ints
  a.bboff  = (int*)(ws + 39203152);           // NB+1 ints
  a.bcur   = (int*)(ws + 39206288);           // NB ints
  a.WpH = (_Float16*)(ws + 39210000);         // 16 KB
  a.WpL = (_Float16*)(ws + 39226384);
  a.W1H = (_Float16*)(ws + 39242768);         // 8 KB each
  a.W1L = (_Float16*)(ws + 39250960);
  a.W2H = (_Float16*)(ws + 39259152);
  a.W2L = (_Float16*)(ws + 39267344);
  a.W3H = (_Float16*)(ws + 39275536);
  a.W3L = (_Float16*)(ws + 39283728);

  (void)hipMemsetAsync(a.bsz, 0, NB * sizeof(int), stream);
  f_prep_bhist<<<276, 256, 0, stream>>>(a);
  f_bscan<<<1, 256, 0, stream>>>(a);
  f_partition<<<196, 256, 0, stream>>>(a);
  f_csrdeg_gemm<<<1564, 256, 0, stream>>>(a);
  f_aggw<0><<<NGROUP16, 256, 0, stream>>>(a, a.bufA16, a.W1H, a.W1L, a.b1, a.hw16, nullptr);
  f_aggw<0><<<NGROUP16, 256, 0, stream>>>(a, a.hw16, a.W2H, a.W2L, a.b2, a.bufA16, nullptr);
  f_aggw<1><<<NGROUP16, 256, 0, stream>>>(a, a.bufA16, a.W3H, a.W3L, a.b3, nullptr, a.out);
}

// Round 12
// 312.459 us; speedup vs baseline: 1.3806x; 1.0487x over previous
//
#include <hip/hip_runtime.h>

#define N_NODES 100000
#define N_EDGES 1600000
#define IN_DIM 128
#define HID 64
#define NB 782               // ceil(100000 / 128) buckets of 128 nodes
#define BCAP 2560            // padded bucket capacity (mean 2048, +11 sigma)
#define NGROUP16 6250        // N_NODES / 16 fused-agg blocks

typedef __attribute__((ext_vector_type(8))) _Float16 h8v;
typedef __attribute__((ext_vector_type(4))) float f4v;

struct Args {
  const float* x; const int* ei;
  const float* Wp; const float* bp;
  const float* W1; const float* b1;
  const float* W2; const float* b2;
  const float* W3; const float* b3;
  float* out;
  _Float16* bufA16; _Float16* hw16;
  int* pairs; int* csr; int* offs; int* deg; float* dinv;
  int* bsz;
  _Float16* WpH; _Float16* WpL; _Float16* W1H; _Float16* W1L;
  _Float16* W2H; _Float16* W2L; _Float16* W3H; _Float16* W3L;
};

// f16(lo/hi half of dword) * f32 + f32 accumulate, single VALU op
__device__ __forceinline__ void fmix_lo(float& acc, unsigned hv, float w) {
  asm("v_fma_mix_f32 %0, %1, %2, %0 op_sel:[0,0,0] op_sel_hi:[1,0,0]"
      : "+v"(acc) : "v"(hv), "v"(w));
}
__device__ __forceinline__ void fmix_hi(float& acc, unsigned hv, float w) {
  asm("v_fma_mix_f32 %0, %1, %2, %0 op_sel:[1,0,0] op_sel_hi:[1,0,0]"
      : "+v"(acc) : "v"(hv), "v"(w));
}

// ---------------- weight prep: split fp32 W[K][64] -> transposed half hi/lo ----
__device__ __forceinline__ void d_split(const float* __restrict__ W,
                                        _Float16* __restrict__ hi,
                                        _Float16* __restrict__ lo, int K, int i) {
  int k = i >> 6, n = i & 63;
  float v = W[i];
  _Float16 h = (_Float16)v;
  float r = v - (float)h;
  hi[n * K + k] = h;
  lo[n * K + k] = (_Float16)r;
}

// ---- fused: partition into PADDED buckets (0..195) | weight prep (196..275) --
// Padded bucket slots (BCAP each) remove the bhist/bscan dependency entirely:
// block reserves its bucket range via atomicAdd(bsz[b], cnt); global order
// within a bucket is irrelevant (csrdeg re-sorts by node locally).
__global__ __launch_bounds__(256) void f_part_prep(Args a) {
  __shared__ int cnt[NB];
  __shared__ int base[NB];
  int blk = blockIdx.x, t = threadIdx.x;
  if (blk >= 196) {  // ---- prep branch (independent) ----
    int b2 = blk - 196;
    if (b2 < 32) d_split(a.Wp, a.WpH, a.WpL, IN_DIM, b2 * 256 + t);
    else if (b2 < 48) d_split(a.W1, a.W1H, a.W1L, HID, (b2 - 32) * 256 + t);
    else if (b2 < 64) d_split(a.W2, a.W2H, a.W2L, HID, (b2 - 48) * 256 + t);
    else d_split(a.W3, a.W3H, a.W3L, HID, (b2 - 64) * 256 + t);
    return;  // block-uniform branch; no barrier crossed
  }
  // ---- partition branch ----
  for (int i = t; i < NB; i += 256) cnt[i] = 0;
  __syncthreads();
  int e0 = blk * 8192, e1 = min(e0 + 8192, N_EDGES);
  for (int e = e0 + t; e < e1; e += 256)
    atomicAdd(&cnt[a.ei[N_EDGES + e] >> 7], 1);
  __syncthreads();
  for (int i = t; i < NB; i += 256) {
    int c = cnt[i];
    base[i] = c ? (i * BCAP + atomicAdd(&a.bsz[i], c)) : 0;
    cnt[i] = 0;
  }
  __syncthreads();
  for (int e = e0 + t; e < e1; e += 256) {
    int s = a.ei[e];
    int d = a.ei[N_EDGES + e];
    int b = d >> 7;
    int r = atomicAdd(&cnt[b], 1);
    a.pairs[base[b] + r] = ((d & 127) << 17) | s;
  }
}

// ---------------- csrdeg body (smem: 3*128 ints), padded-bucket version -------
// csr stores src << 7 (byte offset of the 128B fp16 row); offs points into the
// padded csr; deg[] carries the per-node count (offs[node+1] invalid across pads)
__device__ __forceinline__ void d_csrdeg(Args& a, int b, char* smem) {
  int* ldeg = (int*)smem;
  int* sc = ldeg + 128;
  int* lcur = sc + 128;
  int t = threadIdx.x;
  int node0 = b << 7;
  int nloc = min(128, N_NODES - node0);
  int beg = b * BCAP;
  int end = beg + a.bsz[b];
  if (t < 128) ldeg[t] = 0;
  __syncthreads();
  for (int i = beg + t; i < end; i += 256)
    atomicAdd(&ldeg[(a.pairs[i] >> 17) & 127], 1);
  __syncthreads();
  int dv = (t < 128) ? ldeg[t] : 0;
  if (t < 128) sc[t] = dv;
  __syncthreads();
  for (int off = 1; off < 128; off <<= 1) {
    int u = (t >= off && t < 128) ? sc[t - off] : 0;
    __syncthreads();
    if (t < 128) sc[t] += u;
    __syncthreads();
  }
  if (t < nloc) {
    int o = beg + sc[t] - dv;
    a.offs[node0 + t] = o;
    a.deg[node0 + t] = dv;
    lcur[t] = o;
    a.dinv[node0 + t] = rsqrtf((float)dv + 1.0f);
  }
  __syncthreads();
  for (int i = beg + t; i < end; i += 256) {
    int p = a.pairs[i];
    int pos = atomicAdd(&lcur[(p >> 17) & 127], 1);
    a.csr[pos] = (p & 131071) << 7;
  }
}

// ---------------- gemm_pre body (smem: 32 KB swizzled weights) ----------------
__device__ __forceinline__ void d_gemm_pre(Args& a, int blk, char* smem) {
  _Float16* sW = (_Float16*)smem;  // hi | lo halves, XOR-swizzled
  int t = threadIdx.x;
  int wave = t >> 6, lane = t & 63, fi = lane & 15, quad = lane >> 4;
  int r0 = blk * 128 + wave * 32;

  f4v xb0[8], xb1[8];
  {
    int row = r0 + fi; if (row >= N_NODES) row = N_NODES - 1;
    const float* xp = a.x + (size_t)row * IN_DIM + quad * 8;
#pragma unroll
    for (int j = 0; j < 4; ++j) {
      xb0[2 * j]     = *(const f4v*)(xp + j * 32);
      xb0[2 * j + 1] = *(const f4v*)(xp + j * 32 + 4);
    }
  }
#pragma unroll
  for (int i = 0; i < 8; ++i) {
    int c = i * 256 + t;               // 0..2047
    int h = c >> 10;                   // 0 = hi, 1 = lo
    int c2 = c & 1023;                 // chunk within half
    int n = c2 >> 4;                   // output-col row (16 chunks per row)
    const _Float16* src = (h ? a.WpL : a.WpH) + c2 * 8;
    f4v v = *(const f4v*)src;
    int off = (h << 14) | ((c2 * 16) ^ ((n & 7) << 4));
    *(f4v*)((char*)sW + off) = v;
  }
  __syncthreads();

  float bv[4];
#pragma unroll
  for (int ct = 0; ct < 4; ++ct) bv[ct] = a.bp[ct * 16 + fi];

#pragma unroll
  for (int f = 0; f < 2; ++f) {
    f4v* xcur = (f & 1) ? xb1 : xb0;
    f4v* xnxt = (f & 1) ? xb0 : xb1;
    if (f < 1) {
      int row = r0 + 16 + fi; if (row >= N_NODES) row = N_NODES - 1;
      const float* xp = a.x + (size_t)row * IN_DIM + quad * 8;
#pragma unroll
      for (int j = 0; j < 4; ++j) {
        xnxt[2 * j]     = *(const f4v*)(xp + j * 32);
        xnxt[2 * j + 1] = *(const f4v*)(xp + j * 32 + 4);
      }
    }
    f4v acc[4];
#pragma unroll
    for (int ct = 0; ct < 4; ++ct) acc[ct] = (f4v){0.f, 0.f, 0.f, 0.f};
#pragma unroll
    for (int k0i = 0; k0i < 4; ++k0i) {
      h8v ah, al;
#pragma unroll
      for (int j = 0; j < 4; ++j) {
        float v0 = xcur[2 * k0i][j], v1 = xcur[2 * k0i + 1][j];
        _Float16 h0 = (_Float16)v0, h1 = (_Float16)v1;
        ah[j] = h0;     al[j] = (_Float16)(v0 - (float)h0);
        ah[4 + j] = h1; al[4 + j] = (_Float16)(v1 - (float)h1);
      }
#pragma unroll
      for (int ct = 0; ct < 4; ++ct) {
        int n = ct * 16 + fi;
        int bo = ((n * IN_DIM + k0i * 32 + quad * 8) * 2) ^ ((n & 7) << 4);
        h8v bh = *(const h8v*)((const char*)sW + bo);
        h8v bl = *(const h8v*)((const char*)sW + 16384 + bo);
        acc[ct] = __builtin_amdgcn_mfma_f32_16x16x32_f16(ah, bh, acc[ct], 0, 0, 0);
        acc[ct] = __builtin_amdgcn_mfma_f32_16x16x32_f16(al, bh, acc[ct], 0, 0, 0);
        acc[ct] = __builtin_amdgcn_mfma_f32_16x16x32_f16(ah, bl, acc[ct], 0, 0, 0);
      }
    }
    int ro = r0 + f * 16;
#pragma unroll
    for (int ct = 0; ct < 4; ++ct) {
#pragma unroll
      for (int j = 0; j < 4; ++j) {
        int orow = ro + quad * 4 + j;
        if (orow < N_NODES)
          a.bufA16[(size_t)orow * HID + ct * 16 + fi] = (_Float16)(acc[ct][j] + bv[ct]);
      }
    }
  }
}

// ---- fused: csrdeg (even blocks) | gemm_pre (odd blocks) ---------------------
__global__ __launch_bounds__(256) void f_csrdeg_gemm(Args a) {
  __shared__ char smem[32768];
  int bid = blockIdx.x;
  if (bid & 1) d_gemm_pre(a, bid >> 1, smem);
  else d_csrdeg(a, bid >> 1, smem);
}

// ---- fused aggregate + GEMM (R5/R10 16-node version, proven) -----------------
// agg(h W) == (agg h) W. Block = 16 nodes (4 waves x 4 nodes sequential).
template <int MODE>
__global__ __launch_bounds__(256) void f_aggw(Args a, const _Float16* __restrict__ hsrc,
                                              const _Float16* __restrict__ Wh,
                                              const _Float16* __restrict__ Wl,
                                              const float* __restrict__ bias,
                                              _Float16* __restrict__ out16,
                                              float* __restrict__ out32) {
  __shared__ char sG[2][2048];     // [hi|lo][16 rows x 128B], byte ^= (row&7)<<4
  __shared__ float sSS[4][16];     // per-wave partial sum-of-squares (MODE 1)
  int t = threadIdx.x;
  int wave = t >> 6, lane = t & 63, oct = lane >> 3, fi = lane & 7;
  int node0 = blockIdx.x * 16;     // N_NODES == 6250*16, no bounds checks
  const char* hwb = (const char*)hsrc;
  int lb = fi * 16;

  for (int n = 0; n < 4; ++n) {
    int node = node0 + wave * 4 + n;
    float di = a.dinv[node];
    int beg = a.offs[node];
    int end = beg + a.deg[node];
    float acc[8];
#pragma unroll
    for (int c = 0; c < 8; ++c) acc[c] = 0.f;

    if (oct == 0) {  // self-loop: h_self * di (post-scale by di -> di^2)
      uint4 hv = *(const uint4*)(hwb + ((size_t)node << 7) + lb);
      fmix_lo(acc[0], hv.x, di); fmix_hi(acc[1], hv.x, di);
      fmix_lo(acc[2], hv.y, di); fmix_hi(acc[3], hv.y, di);
      fmix_lo(acc[4], hv.z, di); fmix_hi(acc[5], hv.z, di);
      fmix_lo(acc[6], hv.w, di); fmix_hi(acc[7], hv.w, di);
    }
    for (int e0 = beg + oct; e0 < end; e0 += 16) {
      int off0 = a.csr[e0];
      int e1 = e0 + 8;
      bool v1 = e1 < end;
      int off1 = a.csr[v1 ? e1 : beg];
      float w0 = a.dinv[(unsigned)off0 >> 7];
      float w1 = v1 ? a.dinv[(unsigned)off1 >> 7] : 0.0f;
      uint4 h0 = *(const uint4*)(hwb + (unsigned)off0 + lb);
      uint4 h1 = *(const uint4*)(hwb + (unsigned)off1 + lb);
      fmix_lo(acc[0], h0.x, w0); fmix_hi(acc[1], h0.x, w0);
      fmix_lo(acc[2], h0.y, w0); fmix_hi(acc[3], h0.y, w0);
      fmix_lo(acc[4], h0.z, w0); fmix_hi(acc[5], h0.z, w0);
      fmix_lo(acc[6], h0.w, w0); fmix_hi(acc[7], h0.w, w0);
      fmix_lo(acc[0], h1.x, w1); fmix_hi(acc[1], h1.x, w1);
      fmix_lo(acc[2], h1.y, w1); fmix_hi(acc[3], h1.y, w1);
      fmix_lo(acc[4], h1.z, w1); fmix_hi(acc[5], h1.z, w1);
      fmix_lo(acc[6], h1.w, w1); fmix_hi(acc[7], h1.w, w1);
    }
#pragma unroll
    for (int c = 0; c < 8; ++c) {
      float v = acc[c];
      v += __shfl_xor(v, 8);
      v += __shfl_xor(v, 16);
      v += __shfl_xor(v, 32);
      acc[c] = v;
    }
    if (oct == 0) {  // g = acc * di, split hi/lo, stage to LDS
      int row = wave * 4 + n;
      h8v gh, gl;
#pragma unroll
      for (int c = 0; c < 8; ++c) {
        float g = acc[c] * di;
        _Float16 h = (_Float16)g;
        gh[c] = h;
        gl[c] = (_Float16)(g - (float)h);
      }
      int off = (row * 128 + fi * 16) ^ ((row & 7) << 4);
      *(h8v*)(&sG[0][0] + off) = gh;
      *(h8v*)(&sG[1][0] + off) = gl;
    }
  }
  __syncthreads();

  // MFMA phase: wave w -> out-ch tile [w*16, w*16+16) for all 16 nodes
  int r15 = lane & 15, quad = lane >> 4;
  f4v acc4 = {0.f, 0.f, 0.f, 0.f};
#pragma unroll
  for (int k0i = 0; k0i < 2; ++k0i) {
    int ao = (r15 * 128 + k0i * 64 + quad * 16) ^ ((r15 & 7) << 4);
    h8v ah = *(const h8v*)(&sG[0][0] + ao);
    h8v al = *(const h8v*)(&sG[1][0] + ao);
    size_t bo = (size_t)(wave * 16 + r15) * HID + k0i * 32 + quad * 8;
    h8v bh = *(const h8v*)(Wh + bo);
    h8v bl = *(const h8v*)(Wl + bo);
    acc4 = __builtin_amdgcn_mfma_f32_16x16x32_f16(ah, bh, acc4, 0, 0, 0);
    acc4 = __builtin_amdgcn_mfma_f32_16x16x32_f16(al, bh, acc4, 0, 0, 0);
    acc4 = __builtin_amdgcn_mfma_f32_16x16x32_f16(ah, bl, acc4, 0, 0, 0);
  }
  // C layout: node = quad*4 + j (block-local), out-ch = wave*16 + r15
  float bv = bias[wave * 16 + r15];
  if (MODE == 0) {
#pragma unroll
    for (int j = 0; j < 4; ++j) {
      int nl = quad * 4 + j;
      out16[(size_t)(node0 + nl) * HID + wave * 16 + r15] =
          (_Float16)fmaxf(acc4[j] + bv, 0.f);
    }
  } else {
    float val[4], ssj[4];
#pragma unroll
    for (int j = 0; j < 4; ++j) { val[j] = acc4[j] + bv; ssj[j] = val[j] * val[j]; }
#pragma unroll
    for (int m = 1; m < 16; m <<= 1) {
#pragma unroll
      for (int j = 0; j < 4; ++j) ssj[j] += __shfl_xor(ssj[j], m);
    }
    if (r15 == 0) {
#pragma unroll
      for (int j = 0; j < 4; ++j) sSS[wave][quad * 4 + j] = ssj[j];
    }
    __syncthreads();
#pragma unroll
    for (int j = 0; j < 4; ++j) {
      int nl = quad * 4 + j;
      float tot = sSS[0][nl] + sSS[1][nl] + sSS[2][nl] + sSS[3][nl];
      float sc = 1.0f / fmaxf(sqrtf(tot), 1e-12f);
      out32[(size_t)(node0 + nl) * HID + wave * 16 + r15] = val[j] * sc;
    }
  }
}

extern "C" void kernel_launch(void* const* d_in, const int* in_sizes, int n_in,
                              void* d_out, int out_size, void* d_ws, size_t ws_size,
                              hipStream_t stream) {
  char* ws = (char*)d_ws;
  Args a;
  a.x  = (const float*)d_in[0];
  a.ei = (const int*)d_in[1];
  a.Wp = (const float*)d_in[2];  a.bp = (const float*)d_in[3];
  a.W1 = (const float*)d_in[4];  a.b1 = (const float*)d_in[5];
  a.W2 = (const float*)d_in[6];  a.b2 = (const float*)d_in[7];
  a.W3 = (const float*)d_in[8];  a.b3 = (const float*)d_in[9];
  a.out  = (float*)d_out;
  a.bufA16 = (_Float16*)(ws + 0);             // 12.8 MB fp16 activations A0
  a.hw16   = (_Float16*)(ws + 12800000);      // 12.8 MB fp16 activations A1
  a.pairs  = (int*)(ws + 25600000);           // 8.0 MB padded (NB*BCAP ints)
  a.csr    = (int*)(ws + 33607680);           // 8.0 MB padded (src byte offsets)
  a.offs   = (int*)(ws + 41615360);           // N ints (into padded csr)
  a.deg    = (int*)(ws + 42015376);           // N ints
  a.dinv   = (float*)(ws + 42415376);         // 400 KB
  a.bsz    = (int*)(ws + 42815376);           // NB ints
  a.WpH = (_Float16*)(ws + 42820000);         // 16 KB
  a.WpL = (_Float16*)(ws + 42836384);
  a.W1H = (_Float16*)(ws + 42852768);         // 8 KB each
  a.W1L = (_Float16*)(ws + 42860960);
  a.W2H = (_Float16*)(ws + 42869152);
  a.W2L = (_Float16*)(ws + 42877344);
  a.W3H = (_Float16*)(ws + 42885536);
  a.W3L = (_Float16*)(ws + 42893728);

  (void)hipMemsetAsync(a.bsz, 0, NB * sizeof(int), stream);
  f_part_prep<<<276, 256, 0, stream>>>(a);
  f_csrdeg_gemm<<<1564, 256, 0, stream>>>(a);
  f_aggw<0><<<NGROUP16, 256, 0, stream>>>(a, a.bufA16, a.W1H, a.W1L, a.b1, a.hw16, nullptr);
  f_aggw<0><<<NGROUP16, 256, 0, stream>>>(a, a.hw16, a.W2H, a.W2L, a.b2, a.bufA16, nullptr);
  f_aggw<1><<<NGROUP16, 256, 0, stream>>>(a, a.bufA16, a.W3H, a.W3L, a.b3, nullptr, a.out);
}